// Round 1
// baseline (1693.678 us; speedup 1.0000x reference)
//
#include <hip/hip_runtime.h>

#define NPTS 32768
#define NB   16
#define NN   2048
#define KNB  6

// ---------------- squared-norm kernel ----------------
template<int C>
__global__ void sq_kernel(const float* __restrict__ x, float* __restrict__ sq) {
    int i = blockIdx.x * blockDim.x + threadIdx.x;
    if (i >= NPTS) return;
    const float4* r = (const float4*)(x + (size_t)i * C);
    float s = 0.f;
#pragma unroll
    for (int c = 0; c < C / 4; ++c) {
        float4 f = r[c];
        s += f.x * f.x + f.y * f.y + f.z * f.z + f.w * f.w;
    }
    sq[i] = s;
}

// ---------------- kNN kernel ----------------
// block = 256 threads = 4 waves. Block covers 128 queries of one batch tile.
// Wave g scans candidate range [g*512, (g+1)*512) of the batch, keeping per-thread
// top-6 for 2 queries. Partial lists merged through LDS at the end.
template<int C, int TILE>
__global__ __launch_bounds__(256) void knn_kernel(const float* __restrict__ x,
                                                  const float* __restrict__ sq,
                                                  int* __restrict__ nbr) {
    __shared__ float tile[4][TILE * C];
    __shared__ float sqt[4][TILE];
    __shared__ float md[128][24];
    __shared__ int   mi[128][24];

    const int tid  = threadIdx.x;
    const int g    = tid >> 6;
    const int lane = tid & 63;
    const int b     = blockIdx.y;
    const int qtile = blockIdx.x;      // 0..15
    const int base  = b * NN;          // global row base of this batch
    const int q0 = qtile * 128 + lane; // batch-local query indices
    const int q1 = q0 + 64;

    // query features in registers
    float qa[C], qb[C];
    {
        const float* xq0 = x + (size_t)(base + q0) * C;
        const float* xq1 = x + (size_t)(base + q1) * C;
#pragma unroll
        for (int c = 0; c < C; c += 4) {
            float4 f = *(const float4*)(xq0 + c);
            qa[c] = f.x; qa[c + 1] = f.y; qa[c + 2] = f.z; qa[c + 3] = f.w;
            float4 h = *(const float4*)(xq1 + c);
            qb[c] = h.x; qb[c + 1] = h.y; qb[c + 2] = h.z; qb[c + 3] = h.w;
        }
    }

    float da[6], db[6];
    int   ia[6], ib[6];
#pragma unroll
    for (int k = 0; k < 6; ++k) { da[k] = 1e30f; db[k] = 1e30f; ia[k] = -1; ib[k] = -1; }

    const int nTiles = 512 / TILE;
    for (int t = 0; t < nTiles; ++t) {
        const int jbase = g * 512 + t * TILE;  // batch-local candidate base
        // stage TILE x C floats into this wave's private LDS tile (no barrier needed:
        // only this wave touches tile[g]; compiler orders ds_write->ds_read via waitcnt)
        {
            const float4* src = (const float4*)(x + (size_t)(base + jbase) * C);
            float4* dst = (float4*)tile[g];
#pragma unroll
            for (int k = 0; k < (TILE * C / 4) / 64; ++k)
                dst[lane + 64 * k] = src[lane + 64 * k];
            if (lane < TILE) sqt[g][lane] = sq[base + jbase + lane];
        }
        for (int jj = 0; jj < TILE; ++jj) {
            const float4* row = (const float4*)&tile[g][jj * C];
            float a0 = 0.f, a1 = 0.f, c0 = 0.f, c1 = 0.f;
#pragma unroll
            for (int c4 = 0; c4 < C / 4; ++c4) {
                float4 f = row[c4];
                a0 += f.x * qa[4 * c4]     + f.y * qa[4 * c4 + 1];
                a1 += f.z * qa[4 * c4 + 2] + f.w * qa[4 * c4 + 3];
                c0 += f.x * qb[4 * c4]     + f.y * qb[4 * c4 + 1];
                c1 += f.z * qb[4 * c4 + 2] + f.w * qb[4 * c4 + 3];
            }
            const int j = jbase + jj;
            const float sj = sqt[g][jj];
            const float s0 = sj - 2.f * (a0 + a1);
            const float s1 = sj - 2.f * (c0 + c1);
            if (j != q0 && s0 < da[5]) {
                da[5] = s0; ia[5] = j;
#pragma unroll
                for (int k = 4; k >= 0; --k) {
                    if (da[k + 1] < da[k]) {
                        float td = da[k]; da[k] = da[k + 1]; da[k + 1] = td;
                        int   ti = ia[k]; ia[k] = ia[k + 1]; ia[k + 1] = ti;
                    }
                }
            }
            if (j != q1 && s1 < db[5]) {
                db[5] = s1; ib[5] = j;
#pragma unroll
                for (int k = 4; k >= 0; --k) {
                    if (db[k + 1] < db[k]) {
                        float td = db[k]; db[k] = db[k + 1]; db[k + 1] = td;
                        int   ti = ib[k]; ib[k] = ib[k + 1]; ib[k + 1] = ti;
                    }
                }
            }
        }
    }

    // publish partial lists
#pragma unroll
    for (int k = 0; k < 6; ++k) {
        md[lane][g * 6 + k]      = da[k];
        mi[lane][g * 6 + k]      = ia[k];
        md[lane + 64][g * 6 + k] = db[k];
        mi[lane + 64][g * 6 + k] = ib[k];
    }
    __syncthreads();

    // merge 4x6 -> 6 (lowest distance, ties by lowest index, matching jax top_k)
    if (tid < 128) {
        const int qloc = qtile * 128 + tid;
        int* outp = nbr + (size_t)(base + qloc) * KNB;
#pragma unroll
        for (int k = 0; k < KNB; ++k) {
            float best = 1e38f; int bi = 0x7fffffff; int be = 0;
            for (int e = 0; e < 24; ++e) {
                float d = md[tid][e];
                int   ii = mi[tid][e];
                if (d < best || (d == best && ii < bi)) { best = d; bi = ii; be = e; }
            }
            md[tid][be] = 1e38f;
            outp[k] = base + bi;  // store global row index
        }
    }
}

// ---------------- edge MLP kernel ----------------
// block = 64 threads = 1 wave per point (grid-stride). lane = output channel.
// W1/W2 columns live in registers; msg & h1 round-trip through per-block LDS.
template<int CIN, int COUT, bool RESID>
__global__ __launch_bounds__(64) void mlp_kernel(const float* __restrict__ xin,
                                                 const int* __restrict__ nbr,
                                                 const float* __restrict__ W1,
                                                 const float* __restrict__ b1,
                                                 const float* __restrict__ W2,
                                                 const float* __restrict__ b2,
                                                 const float* __restrict__ resid,
                                                 float* __restrict__ out) {
    const int lane = threadIdx.x;
    const int o = lane & (COUT - 1);

    float w1c[2 * CIN];
    float w2c[COUT];
#pragma unroll
    for (int c = 0; c < 2 * CIN; ++c) w1c[c] = W1[c * COUT + o];
#pragma unroll
    for (int c = 0; c < COUT; ++c) w2c[c] = W2[c * COUT + o];
    const float b1v = b1[o];
    const float b2v = b2[o];

    __shared__ __align__(16) float msg[2 * CIN];
    __shared__ __align__(16) float h1[COUT];

    for (int i = blockIdx.x; i < NPTS; i += gridDim.x) {
        float xiv = 0.f;
        if (lane < CIN) {
            xiv = xin[(size_t)i * CIN + lane];
            msg[lane] = xiv;
        }
        float best = -1e38f;
        for (int n = 0; n < KNB; ++n) {
            const int j = nbr[i * KNB + n];
            if (lane < CIN) msg[CIN + lane] = xin[(size_t)j * CIN + lane] - xiv;
            __syncthreads();  // single-wave block: cheap; guarantees LDS visibility
            float acc0 = b1v, acc1 = 0.f;
#pragma unroll
            for (int c4 = 0; c4 < (2 * CIN) / 4; ++c4) {
                float4 f = ((const float4*)msg)[c4];
                acc0 += f.x * w1c[4 * c4]     + f.y * w1c[4 * c4 + 1];
                acc1 += f.z * w1c[4 * c4 + 2] + f.w * w1c[4 * c4 + 3];
            }
            const float h = fmaxf(acc0 + acc1, 0.f);
            __syncthreads();
            if (lane < COUT) h1[lane] = h;
            __syncthreads();
            float a0 = b2v, a1 = 0.f;
#pragma unroll
            for (int c4 = 0; c4 < COUT / 4; ++c4) {
                float4 f = ((const float4*)h1)[c4];
                a0 += f.x * w2c[4 * c4]     + f.y * w2c[4 * c4 + 1];
                a1 += f.z * w2c[4 * c4 + 2] + f.w * w2c[4 * c4 + 3];
            }
            best = fmaxf(best, a0 + a1);
            __syncthreads();
        }
        if (lane < COUT) {
            float v = best;
            if (RESID) v += resid[(size_t)i * 64 + lane];
            v = fmaxf(v, 0.f);
            out[(size_t)i * COUT + lane] = v;
        }
    }
}

extern "C" void kernel_launch(void* const* d_in, const int* in_sizes, int n_in,
                              void* d_out, int out_size, void* d_ws, size_t ws_size,
                              hipStream_t stream) {
    const float* x    = (const float*)d_in[0];
    // d_in[1] = batch (unused; B fixed at 16)
    const float* W1_0 = (const float*)d_in[2];
    const float* b1_0 = (const float*)d_in[3];
    const float* W2_0 = (const float*)d_in[4];
    const float* b2_0 = (const float*)d_in[5];
    const float* W1_1 = (const float*)d_in[6];
    const float* b1_1 = (const float*)d_in[7];
    const float* W2_1 = (const float*)d_in[8];
    const float* b2_1 = (const float*)d_in[9];
    const float* W1_2 = (const float*)d_in[10];
    const float* b1_2 = (const float*)d_in[11];
    const float* W2_2 = (const float*)d_in[12];
    const float* b2_2 = (const float*)d_in[13];
    float* outp = (float*)d_out;

    // workspace layout
    float* x0  = (float*)d_ws;                 // 32768 x 64
    float* x1  = x0 + (size_t)NPTS * 64;       // 32768 x 32
    float* sqb = x1 + (size_t)NPTS * 32;       // 32768
    int*   nbr = (int*)(sqb + NPTS);           // 32768 x 6

    const dim3 kgrid(16, 16);

    // ---- layer 0: x (32) -> x0 (64), relu ----
    sq_kernel<32><<<NPTS / 256, 256, 0, stream>>>(x, sqb);
    knn_kernel<32, 64><<<kgrid, 256, 0, stream>>>(x, sqb, nbr);
    mlp_kernel<32, 64, false><<<2048, 64, 0, stream>>>(x, nbr, W1_0, b1_0, W2_0, b2_0, nullptr, x0);

    // ---- layer 1: x0 (64) -> x1 (32), relu ----
    sq_kernel<64><<<NPTS / 256, 256, 0, stream>>>(x0, sqb);
    knn_kernel<64, 32><<<kgrid, 256, 0, stream>>>(x0, sqb, nbr);
    mlp_kernel<64, 32, false><<<2048, 64, 0, stream>>>(x0, nbr, W1_1, b1_1, W2_1, b2_1, nullptr, x1);

    // ---- layer 2: x1 (32) -> out (64), +x0 residual, relu ----
    sq_kernel<32><<<NPTS / 256, 256, 0, stream>>>(x1, sqb);
    knn_kernel<32, 64><<<kgrid, 256, 0, stream>>>(x1, sqb, nbr);
    mlp_kernel<32, 64, true><<<2048, 64, 0, stream>>>(x1, nbr, W1_2, b1_2, W2_2, b2_2, x0, outp);
}